// Round 14
// baseline (272.999 us; speedup 1.0000x reference)
//
#include <hip/hip_runtime.h>
#include <hip/hip_fp8.h>
#include <math.h>

#define NUM_USERS 100000
#define NUM_ITEMS 200000
#define N_NODES   300000   // NUM_USERS + NUM_ITEMS
#define EMB       64
#define NUM_INTER 1000000
#define BATCH     16384

// ---- bucketed CSR builder geometry ----
#define BSHIFT 9
#define BNODES 512
#define NBKT   ((N_NODES + BNODES - 1) / BNODES)    // 586
#define CAP    6144       // refs per bucket (max expected ~5400)
#define RSHIFT 13         // fixed nbr region per bucket: 8192 slots (max padded use 7680)
#define RSLOTS (1 << RSHIFT)

// pass-A dispatch: 1024-thread blocks; scatter blocks FIRST (critical path)
#define EDGES_PER_BLOCK 4096                        // 143K aggregated cursor atomics (proven)
#define SCAT_BLOCKS ((NUM_INTER + EDGES_PER_BLOCK - 1) / EDGES_PER_BLOCK)   // 245
#define QMARK_BLOCKS ((BATCH * 2) / 1024)           // 32
#define CONV_BLOCKS ((N_NODES * 8 + 1023) / 1024)   // 2344
#define QMARK_BASE  SCAT_BLOCKS                     // 245
#define MISC_BLOCK  (QMARK_BASE + QMARK_BLOCKS)     // 277
#define CONV_BASE   (MISC_BLOCK + 1)                // 278

#define PROP4_BLOCKS ((N_NODES * 4 + 255) / 256)    // 4688: 4 threads/node gathers

typedef int      vint4   __attribute__((ext_vector_type(4)));
typedef _Float16 half8   __attribute__((ext_vector_type(8)));
typedef float    floatx2 __attribute__((ext_vector_type(2)));

// pair code: (local_node_in_bucket << 19) | partner   (local<512, partner<2^19)
#define PMASK 0x7FFFFu

// fp8 e4m3 staging for semb: stores fp8(emb * 256); 2^-8 folded into z1 scale.
// z1 int8 with per-row scale; z2 fp16. (R8: both-z-fp8 = 1.603e-6 > thr 1.373e-6;
// this mix = 8.94e-7, passes.)
#define FP8_SCALE    256.0f
#define FP8_INVSCALE (1.0f / 256.0f)

// HW packed conversions (gfx950 OCP e4m3): 2 fp8 <-> 2 f32 per instruction.
template<bool HI>
__device__ __forceinline__ floatx2 fp8d2(unsigned v) {
    return __builtin_amdgcn_cvt_pk_f32_fp8((int)v, HI);
}
__device__ __forceinline__ unsigned fp8pack4(float a, float b, float c, float d) {
    int lo = __builtin_amdgcn_cvt_pk_fp8_f32(a, b, 0, false);
    return (unsigned)__builtin_amdgcn_cvt_pk_fp8_f32(c, d, lo, true);
}
__device__ __forceinline__ float i8d(unsigned v) {    // low byte as signed -> float
    return (float)(signed char)(v & 0xffu);
}

// ---------- pass A (1024-thread blocks): scatter FIRST, then qmark/misc/conv ----------
__global__ __launch_bounds__(1024) void bucket_scatter_k(
        const int* __restrict__ iu, const int* __restrict__ ii,
        const int* __restrict__ uid, const int* __restrict__ iid,
        int* __restrict__ cursor /*stride 16 ints*/, unsigned* __restrict__ pairs,
        unsigned char* __restrict__ qflag, unsigned char* __restrict__ flag,
        const float* __restrict__ lw, float* __restrict__ w4,
        float* __restrict__ dinv, float* __restrict__ z1scale,
        const float* __restrict__ ue, const float* __restrict__ ie,
        unsigned char* __restrict__ semb, unsigned char* __restrict__ z1,
        _Float16* __restrict__ z2) {
    int tid = threadIdx.x;
    if (blockIdx.x < SCAT_BLOCKS) {
        __shared__ int hist[NBKT];
        __shared__ int gbase[NBKT];
        int bid = blockIdx.x;
        for (int b = tid; b < NBKT; b += 1024) hist[b] = 0;
        __syncthreads();

        int e0 = bid * EDGES_PER_BLOCK;
        int u[4], it[4];
        unsigned pk[8];
        #pragma unroll
        for (int k = 0; k < 4; ++k) {
            int e = e0 + k * 1024 + tid;
            bool v = (e < NUM_INTER);
            u[k]  = v ? iu[e] : -1;
            it[k] = v ? (NUM_USERS + ii[e]) : -1;
        }
        #pragma unroll
        for (int k = 0; k < 4; ++k) {
            if (u[k] >= 0) {
                int b0 = u[k] >> BSHIFT;
                int r0 = atomicAdd(&hist[b0], 1);
                pk[2 * k] = ((unsigned)b0 << 13) | (unsigned)r0;    // lrank < 8192
                int b1 = it[k] >> BSHIFT;
                int r1 = atomicAdd(&hist[b1], 1);
                pk[2 * k + 1] = ((unsigned)b1 << 13) | (unsigned)r1;
            }
        }
        __syncthreads();
        for (int b = tid; b < NBKT; b += 1024) {
            int c = hist[b];
            if (c) gbase[b] = atomicAdd(&cursor[b * 16], c);
        }
        __syncthreads();
        #pragma unroll
        for (int k = 0; k < 4; ++k) {
            if (u[k] >= 0) {
                unsigned p0 = pk[2 * k];
                int b0 = (int)(p0 >> 13);
                int s0 = gbase[b0] + (int)(p0 & 0x1fffu);
                if (s0 < CAP)
                    pairs[(size_t)b0 * CAP + s0] =
                        ((unsigned)(u[k] & (BNODES - 1)) << 19) | (unsigned)it[k];
                unsigned p1 = pk[2 * k + 1];
                int b1 = (int)(p1 >> 13);
                int s1 = gbase[b1] + (int)(p1 & 0x1fffu);
                if (s1 < CAP)
                    pairs[(size_t)b1 * CAP + s1] =
                        ((unsigned)(it[k] & (BNODES - 1)) << 19) | (unsigned)u[k];
            }
        }
        return;
    }
    if (blockIdx.x < MISC_BLOCK) {
        int t = (blockIdx.x - QMARK_BASE) * 1024 + tid;   // < BATCH*2 exactly
        int node = (t & 1) ? (NUM_USERS + iid[t >> 1]) : uid[t >> 1];
        qflag[node] = 1;
        flag[node]  = 1;                                  // queried nodes need z2 too
        return;
    }
    if (blockIdx.x == MISC_BLOCK) {
        // misc: zero dummy rows (semb/z1 64 B, z2 128 B) + padding slots + softmax
        if (tid < 16)               ((unsigned*)semb)[(size_t)N_NODES * 16 + tid]      = 0u;
        if (tid >= 32 && tid < 48)  ((unsigned*)z1)[(size_t)N_NODES * 16 + (tid - 32)] = 0u;
        if (tid >= 64 && tid < 96)  ((unsigned*)z2)[(size_t)N_NODES * 32 + (tid - 64)] = 0u;
        if (tid == 96) dinv[N_NODES] = 0.0f;          // padding lanes gather dinv[N_NODES]
        if (tid == 97) z1scale[N_NODES] = 0.0f;       // guard: 0 x garbage would NaN
        if (tid == 0) {
            float a = lw[0], b = lw[1], c = lw[2], d = lw[3];
            float m = fmaxf(fmaxf(a, b), fmaxf(c, d));
            float e0 = expf(a - m), e1 = expf(b - m), e2 = expf(c - m), e3 = expf(d - m);
            float sm = e0 + e1 + e2 + e3;
            w4[0] = e0 / sm; w4[1] = e1 / sm; w4[2] = e2 / sm; w4[3] = e3 / sm;
        }
        return;
    }
    // conv: semb[n] = fp8(emb[n] * 256)   (64 B rows, no degree dependency)
    int t = (blockIdx.x - CONV_BASE) * 1024 + tid;
    int node = t >> 3;
    int q = t & 7;
    if (node >= N_NODES) return;
    const float4* src = (node < NUM_USERS)
        ? (const float4*)ue + (size_t)node * 16
        : (const float4*)ie + (size_t)(node - NUM_USERS) * 16;
    float4 f0 = src[q * 2];
    float4 f1 = src[q * 2 + 1];
    unsigned b0 = fp8pack4(f0.x * FP8_SCALE, f0.y * FP8_SCALE,
                           f0.z * FP8_SCALE, f0.w * FP8_SCALE);
    unsigned b1 = fp8pack4(f1.x * FP8_SCALE, f1.y * FP8_SCALE,
                           f1.z * FP8_SCALE, f1.w * FP8_SCALE);
    ((uint2*)semb)[(size_t)node * 8 + q] = make_uint2(b0, b1);
}

// ---------- pass B: bucket-local CSR, 1024 threads, pairs staged in LDS ----------
__global__ __launch_bounds__(1024) void bucket_all_k(
        const int* __restrict__ cursor, const unsigned* __restrict__ pairs,
        const unsigned char* __restrict__ qflag, unsigned char* __restrict__ flag,
        int* __restrict__ deg, float* __restrict__ dinv, float* __restrict__ d2,
        float* __restrict__ rcp, int* __restrict__ row_start, int* __restrict__ nbr) {
    __shared__ unsigned pl[CAP];          // 24 KB: this bucket's pairs (read once)
    __shared__ int cnt[BNODES];
    __shared__ int lofs_s[BNODES];
    __shared__ int sc[BNODES];
    __shared__ unsigned qf[BNODES / 4];
    int b = blockIdx.x, tid = threadIdx.x;
    if (tid < BNODES) cnt[tid] = 0;
    if (tid < BNODES / 4)
        qf[tid] = ((const unsigned*)(qflag + ((size_t)b << BSHIFT)))[tid];
    __syncthreads();
    int n = cursor[b * 16]; if (n > CAP) n = CAP;
    const unsigned* p = pairs + (size_t)b * CAP;
    const unsigned char* qfb = (const unsigned char*)qf;
    for (int j = tid; j < n; j += 1024) {
        unsigned code = p[j];
        pl[j] = code;                         // stage for the scatter pass
        int l = (int)(code >> 19);
        atomicAdd(&cnt[l], 1);
        if (qfb[l]) flag[code & PMASK] = 1;   // neighbor-of-queried
    }
    __syncthreads();

    int c = 0, pd = 0;
    if (tid < BNODES) { c = cnt[tid]; pd = (c + 3) & ~3; sc[tid] = pd; }
    __syncthreads();
    for (int o = 1; o < BNODES; o <<= 1) {
        int x = (tid >= o && tid < BNODES) ? sc[tid - o] : 0;
        __syncthreads();
        if (tid < BNODES) sc[tid] += x;
        __syncthreads();
    }
    if (tid < BNODES) {
        int excl = sc[tid] - pd;
        int g = (b << BSHIFT) + tid;
        if (g < N_NODES) {
            deg[g] = c;
            float fd = (float)c;
            dinv[g] = (c > 0) ? (1.0f / sqrtf(fd)) : 0.0f;
            d2[g]   = (c > 0) ? (1.0f / fd) : 0.0f;
            rcp[g]  = (c > 0) ? sqrtf(fd) : 0.0f;
            row_start[g] = (b << RSHIFT) + excl;
        }
        lofs_s[tid] = excl;
        cnt[tid] = 0;                 // reuse as rank counters
    }
    __syncthreads();

    int nbase = b << RSHIFT;
    for (int j = tid; j < n; j += 1024) {
        unsigned code = pl[j];                // LDS, not global
        int l = (int)(code >> 19);
        int r = atomicAdd(&cnt[l], 1);
        nbr[nbase + lofs_s[l] + r] = (int)(code & PMASK);
    }
}

// ---------- prop layer 1 (4 threads/node, 16B/thread): z1 = int8rowquant(...) ----------
__global__ void prop_first_k(const int* __restrict__ row_start, const int* __restrict__ nbr,
                             const int* __restrict__ deg, const float* __restrict__ d2,
                             const float* __restrict__ dinv,
                             const unsigned char* __restrict__ semb,
                             unsigned char* __restrict__ z1, float* __restrict__ z1scale) {
    int t = blockIdx.x * blockDim.x + threadIdx.x;
    int node = t >> 2;
    int q = t & 3;
    if (node >= N_NODES) return;
    int d = deg[node];
    int beg = row_start[node];
    int lim = beg + d;
    int end = beg + ((d + 3) & ~3);
    const uint4* src = (const uint4*)semb;    // 64 B rows: 4 threads x 16 B
    float a[16];
    #pragma unroll
    for (int i = 0; i < 16; ++i) a[i] = 0.f;
    for (int j = beg; j < end; j += 8) {
        vint4 na = __builtin_nontemporal_load((const vint4*)(nbr + j));
        vint4 nb = __builtin_nontemporal_load((const vint4*)(nbr + j + 4));
        #pragma unroll
        for (int k = 0; k < 8; ++k) {
            int id = (j + k < lim) ? ((k < 4) ? na[k] : nb[k - 4]) : N_NODES;
            float w = dinv[id];                  // dinv[N_NODES] == 0 (misc block)
            uint4 raw = src[(size_t)id * 4 + q];
            floatx2 p0 = fp8d2<false>(raw.x), p1 = fp8d2<true>(raw.x);
            floatx2 p2 = fp8d2<false>(raw.y), p3 = fp8d2<true>(raw.y);
            floatx2 p4 = fp8d2<false>(raw.z), p5 = fp8d2<true>(raw.z);
            floatx2 p6 = fp8d2<false>(raw.w), p7 = fp8d2<true>(raw.w);
            a[0]  += w * p0.x; a[1]  += w * p0.y; a[2]  += w * p1.x; a[3]  += w * p1.y;
            a[4]  += w * p2.x; a[5]  += w * p2.y; a[6]  += w * p3.x; a[7]  += w * p3.y;
            a[8]  += w * p4.x; a[9]  += w * p4.y; a[10] += w * p5.x; a[11] += w * p5.y;
            a[12] += w * p6.x; a[13] += w * p6.y; a[14] += w * p7.x; a[15] += w * p7.y;
        }
    }
    float s = d2[node] * FP8_INVSCALE;           // undo the x256 fp8 staging scale
    float v[16];
    float m = 0.f;
    #pragma unroll
    for (int i = 0; i < 16; ++i) { v[i] = s * a[i]; m = fmaxf(m, fabsf(v[i])); }
    // per-row (64-elem) max across this node's 4 lanes
    m = fmaxf(m, __shfl_xor(m, 1));
    m = fmaxf(m, __shfl_xor(m, 2));
    float inv = (m > 0.f) ? (127.0f / m) : 0.0f;
    int b[16];
    #pragma unroll
    for (int i = 0; i < 16; ++i) b[i] = __float2int_rn(v[i] * inv);
    uint4 o;
    o.x = (unsigned)(b[0]  & 255) | ((unsigned)(b[1]  & 255) << 8)
        | ((unsigned)(b[2]  & 255) << 16) | ((unsigned)(b[3]  & 255) << 24);
    o.y = (unsigned)(b[4]  & 255) | ((unsigned)(b[5]  & 255) << 8)
        | ((unsigned)(b[6]  & 255) << 16) | ((unsigned)(b[7]  & 255) << 24);
    o.z = (unsigned)(b[8]  & 255) | ((unsigned)(b[9]  & 255) << 8)
        | ((unsigned)(b[10] & 255) << 16) | ((unsigned)(b[11] & 255) << 24);
    o.w = (unsigned)(b[12] & 255) | ((unsigned)(b[13] & 255) << 8)
        | ((unsigned)(b[14] & 255) << 16) | ((unsigned)(b[15] & 255) << 24);
    ((uint4*)z1)[(size_t)node * 4 + q] = o;
    if (q == 0) z1scale[node] = (m > 0.f) ? (m / 127.0f) : 0.0f;
}

// ---------- prop layer 2 (4 threads/node, flag-masked): z2 = fp16(d2 * sum sc*i8z1) ----------
__global__ void prop_masked_k(const int* __restrict__ row_start, const int* __restrict__ nbr,
                              const int* __restrict__ deg, const float* __restrict__ d2,
                              const unsigned char* __restrict__ flag,
                              const unsigned char* __restrict__ in,
                              const float* __restrict__ z1s,
                              _Float16* __restrict__ out) {
    int t = blockIdx.x * blockDim.x + threadIdx.x;
    int node = t >> 2;
    int q = t & 3;
    if (node >= N_NODES) return;
    if (!flag[node]) return;   // z2 never read at unflagged nodes
    int d = deg[node];
    int beg = row_start[node];
    int lim = beg + d;
    int end = beg + ((d + 3) & ~3);
    const uint4* src = (const uint4*)in;      // 64 B int8 rows: 4 threads x 16 B
    float a[16];
    #pragma unroll
    for (int i = 0; i < 16; ++i) a[i] = 0.f;
    for (int j = beg; j < end; j += 8) {
        vint4 na = __builtin_nontemporal_load((const vint4*)(nbr + j));
        vint4 nb = __builtin_nontemporal_load((const vint4*)(nbr + j + 4));
        #pragma unroll
        for (int k = 0; k < 8; ++k) {
            int id = (j + k < lim) ? ((k < 4) ? na[k] : nb[k - 4]) : N_NODES;
            float sc = z1s[id];                // z1scale[N_NODES] == 0
            uint4 raw = src[(size_t)id * 4 + q];
            a[0]  += sc * i8d(raw.x);       a[1]  += sc * i8d(raw.x >> 8);
            a[2]  += sc * i8d(raw.x >> 16); a[3]  += sc * i8d(raw.x >> 24);
            a[4]  += sc * i8d(raw.y);       a[5]  += sc * i8d(raw.y >> 8);
            a[6]  += sc * i8d(raw.y >> 16); a[7]  += sc * i8d(raw.y >> 24);
            a[8]  += sc * i8d(raw.z);       a[9]  += sc * i8d(raw.z >> 8);
            a[10] += sc * i8d(raw.z >> 16); a[11] += sc * i8d(raw.z >> 24);
            a[12] += sc * i8d(raw.w);       a[13] += sc * i8d(raw.w >> 8);
            a[14] += sc * i8d(raw.w >> 16); a[15] += sc * i8d(raw.w >> 24);
        }
    }
    float s = d2[node];
    half8 r0, r1;
    #pragma unroll
    for (int i = 0; i < 8; ++i) r0[i] = (_Float16)(s * a[i]);
    #pragma unroll
    for (int i = 0; i < 8; ++i) r1[i] = (_Float16)(s * a[8 + i]);
    ((half8*)out)[(size_t)node * 8 + q * 2]     = r0;
    ((half8*)out)[(size_t)node * 8 + q * 2 + 1] = r1;
}

// ---------- fused epilogue: layer-3 pull at queried nodes + layers 0-2 + dot ----------
// 16 lanes per (u,i) pair: 8 lanes user side, 8 lanes item side, 8 dims/lane
__global__ void fused_score_k(const int* __restrict__ row_start, const int* __restrict__ nbr,
                              const int* __restrict__ deg,
                              const float* __restrict__ dinv, const float* __restrict__ rcp,
                              const float* __restrict__ ue, const float* __restrict__ ie,
                              const unsigned char* __restrict__ z1,
                              const float* __restrict__ z1s,
                              const _Float16* __restrict__ z2,
                              const int* __restrict__ uid, const int* __restrict__ iid,
                              const float* __restrict__ w4, float* __restrict__ out) {
    int t = blockIdx.x * blockDim.x + threadIdx.x;
    int slot = t >> 4;
    if (slot >= BATCH) return;
    int within = t & 15;
    int side = within >> 3;
    int q = within & 7;

    int node;
    const float4* erow;
    if (side == 0) {
        int u = uid[slot];
        node = u;
        erow = (const float4*)ue + (size_t)u * 16;
    } else {
        int ii_ = iid[slot];
        node = NUM_USERS + ii_;
        erow = (const float4*)ie + (size_t)ii_ * 16;
    }

    float w0 = w4[0], w1 = w4[1], w2 = w4[2], w3 = w4[3];
    int d = deg[node];
    int beg = row_start[node];
    int lim = beg + d;
    int end = beg + ((d + 3) & ~3);
    const half8* z2v = (const half8*)z2;

    float a0 = 0.f, a1 = 0.f, a2 = 0.f, a3 = 0.f, a4 = 0.f, a5 = 0.f, a6 = 0.f, a7 = 0.f;
    for (int j = beg; j < end; j += 8) {
        vint4 na = __builtin_nontemporal_load((const vint4*)(nbr + j));
        vint4 nb = __builtin_nontemporal_load((const vint4*)(nbr + j + 4));
        #pragma unroll
        for (int k = 0; k < 8; ++k) {
            int id = (j + k < lim) ? ((k < 4) ? na[k] : nb[k - 4]) : N_NODES;
            half8 h = z2v[(size_t)id * 8 + q];
            a0 += (float)h[0]; a1 += (float)h[1]; a2 += (float)h[2]; a3 += (float)h[3];
            a4 += (float)h[4]; a5 += (float)h[5]; a6 += (float)h[6]; a7 += (float)h[7];
        }
    }

    float r  = rcp[node];
    float di = dinv[node];
    float e[8];
    *reinterpret_cast<float4*>(&e[0]) = erow[q * 2];
    *reinterpret_cast<float4*>(&e[4]) = erow[q * 2 + 1];
    uint2 r1 = ((const uint2*)z1)[(size_t)node * 8 + q];
    float s1 = z1s[node];
    float h1[8] = { s1 * i8d(r1.x),       s1 * i8d(r1.x >> 8),
                    s1 * i8d(r1.x >> 16), s1 * i8d(r1.x >> 24),
                    s1 * i8d(r1.y),       s1 * i8d(r1.y >> 8),
                    s1 * i8d(r1.y >> 16), s1 * i8d(r1.y >> 24) };
    half8 h2 = z2v[(size_t)node * 8 + q];
    float acc[8] = {a0, a1, a2, a3, a4, a5, a6, a7};

    float f[8];
    #pragma unroll
    for (int dd = 0; dd < 8; ++dd)
        f[dd] = w0 * e[dd] + r * (w1 * h1[dd] + w2 * (float)h2[dd]) + w3 * di * acc[dd];

    float pr = 0.f;
    #pragma unroll
    for (int dd = 0; dd < 8; ++dd) {
        float o = __shfl_xor(f[dd], 8);   // partner side, same dims
        pr += f[dd] * o;
    }
    pr += __shfl_xor(pr, 1);
    pr += __shfl_xor(pr, 2);
    pr += __shfl_xor(pr, 4);

    if (within == 0) out[slot] = pr;
}

// ---------- launch ----------

extern "C" void kernel_launch(void* const* d_in, const int* in_sizes, int n_in,
                              void* d_out, int out_size, void* d_ws, size_t ws_size,
                              hipStream_t stream) {
    const float* user_emb = (const float*)d_in[0];
    const float* item_emb = (const float*)d_in[1];
    const float* layer_w  = (const float*)d_in[2];
    const int*   inter_u  = (const int*)d_in[3];
    const int*   inter_i  = (const int*)d_in[4];
    const int*   user_ids = (const int*)d_in[5];
    const int*   item_ids = (const int*)d_in[6];
    float* out = (float*)d_out;

    char* base = (char*)d_ws;
    size_t off = 0;
    auto alloc = [&](size_t bytes) -> char* {
        char* p = base + off;
        off = (off + bytes + 255) & ~(size_t)255;
        return p;
    };
    float*    w4        = (float*)    alloc(4 * sizeof(float));
    int*      deg       = (int*)      alloc((size_t)N_NODES * sizeof(int));
    float*    dinv      = (float*)    alloc(((size_t)N_NODES + 1) * sizeof(float));  // +1: padding slot
    float*    d2        = (float*)    alloc((size_t)N_NODES * sizeof(float));
    float*    rcp       = (float*)    alloc((size_t)N_NODES * sizeof(float));
    float*    z1scale   = (float*)    alloc(((size_t)N_NODES + 1) * sizeof(float));  // +1: padding slot
    int*      row_start = (int*)      alloc((size_t)N_NODES * sizeof(int));
    // zeroed region: flag + qflag + cursor (adjacent; single memset)
    unsigned char* flag   = (unsigned char*)alloc((size_t)N_NODES + 256);
    unsigned char* qflag  = (unsigned char*)alloc((size_t)N_NODES + 512);
    int*           cursor = (int*)          alloc((size_t)NBKT * 16 * sizeof(int));
    unsigned* pairs     = (unsigned*) alloc((size_t)NBKT * CAP * sizeof(unsigned));
    int*      csr_nbr   = (int*)      alloc((size_t)NBKT * RSLOTS * sizeof(int));
    unsigned char* semb = (unsigned char*)alloc(((size_t)N_NODES + 1) * EMB);        // fp8 e4m3
    unsigned char* zB   = (unsigned char*)alloc(((size_t)N_NODES + 1) * EMB);        // int8 z1
    _Float16* zA        = (_Float16*) alloc(((size_t)N_NODES + 1) * EMB * sizeof(_Float16)); // fp16 z2

    // 1. zero flag + qflag + bucket cursors (adjacent allocations, single memset)
    size_t span = (size_t)((char*)cursor - (char*)flag) + (size_t)NBKT * 16 * sizeof(int);
    (void)hipMemsetAsync(flag, 0, span, stream);

    // 2. scatter-first 1024-thread dispatch: scatter + qmark + misc + fp8 emb cast
    bucket_scatter_k<<<CONV_BASE + CONV_BLOCKS, 1024, 0, stream>>>(
        inter_u, inter_i, user_ids, item_ids, cursor, pairs, qflag, flag,
        layer_w, w4, dinv, z1scale, user_emb, item_emb, semb, zB, zA);

    // 3. bucket-local CSR: degrees + factors + row_start + scatter (LDS-staged pairs)
    bucket_all_k<<<NBKT, 1024, 0, stream>>>(
        cursor, pairs, qflag, flag, deg, dinv, d2, rcp, row_start, csr_nbr);

    // 4. layer 1 full (fp8 gather via HW cvt, int8 row-quant z1 out, 4 thr/node): zB = z1
    prop_first_k<<<PROP4_BLOCKS, 256, 0, stream>>>(
        row_start, csr_nbr, deg, d2, dinv, semb, zB, z1scale);

    // 5. layer 2 flag-masked (int8 z1 gather, fp16 z2 out, 4 thr/node): zA = z2
    prop_masked_k<<<PROP4_BLOCKS, 256, 0, stream>>>(
        row_start, csr_nbr, deg, d2, flag, zB, z1scale, zA);

    // 6. fused: layer-3 pull at queried nodes + layer 0-2 terms + dot product
    fused_score_k<<<(BATCH * 16 + 255) / 256, 256, 0, stream>>>(
        row_start, csr_nbr, deg, dinv, rcp, user_emb, item_emb,
        zB /*z1*/, z1scale, zA /*z2*/, user_ids, item_ids, w4, out);
}

// Round 15
// 251.257 us; speedup vs baseline: 1.0865x; 1.0865x over previous
//
#include <hip/hip_runtime.h>
#include <hip/hip_fp8.h>
#include <math.h>

#define NUM_USERS 100000
#define NUM_ITEMS 200000
#define N_NODES   300000   // NUM_USERS + NUM_ITEMS
#define EMB       64
#define NUM_INTER 1000000
#define BATCH     16384

// ---- bucketed CSR builder geometry ----
#define BSHIFT 9
#define BNODES 512
#define NBKT   ((N_NODES + BNODES - 1) / BNODES)    // 586
#define CAP    6144       // refs per bucket (max expected ~5400)
#define RSHIFT 13         // fixed nbr region per bucket: 8192 slots (max padded use 7680)
#define RSLOTS (1 << RSHIFT)

// pass-A dispatch: 1024-thread blocks; scatter blocks FIRST (critical path)
#define EDGES_PER_BLOCK 4096                        // 143K aggregated cursor atomics (proven)
#define SCAT_BLOCKS ((NUM_INTER + EDGES_PER_BLOCK - 1) / EDGES_PER_BLOCK)   // 245
#define QMARK_BLOCKS ((BATCH * 2) / 1024)           // 32
#define CONV_BLOCKS ((N_NODES * 8 + 1023) / 1024)   // 2344
#define QMARK_BASE  SCAT_BLOCKS                     // 245
#define MISC_BLOCK  (QMARK_BASE + QMARK_BLOCKS)     // 277
#define CONV_BASE   (MISC_BLOCK + 1)                // 278

#define PROP_BLOCKS ((N_NODES * 8 + 255) / 256)  // 9375

typedef int      vint4   __attribute__((ext_vector_type(4)));
typedef _Float16 half8   __attribute__((ext_vector_type(8)));
typedef float    floatx2 __attribute__((ext_vector_type(2)));

// pair code: (local_node_in_bucket << 19) | partner   (local<512, partner<2^19)
#define PMASK 0x7FFFFu

// fp8 e4m3 staging for semb: stores fp8(emb * 256); 2^-8 folded into z1 scale.
// z1 int8 with per-row scale; z2 fp16. (R8: both-z-fp8 = 1.603e-6 > thr 1.373e-6;
// this mix = 8.94e-7, passes. R14: 4thr/node ILP trade regressed — 8thr/node pinned.)
#define FP8_SCALE    256.0f
#define FP8_INVSCALE (1.0f / 256.0f)

// HW packed conversions (gfx950 OCP e4m3): 2 fp8 <-> 2 f32 per instruction.
template<bool HI>
__device__ __forceinline__ floatx2 fp8d2(unsigned v) {
    return __builtin_amdgcn_cvt_pk_f32_fp8((int)v, HI);
}
__device__ __forceinline__ unsigned fp8pack4(float a, float b, float c, float d) {
    int lo = __builtin_amdgcn_cvt_pk_fp8_f32(a, b, 0, false);
    return (unsigned)__builtin_amdgcn_cvt_pk_fp8_f32(c, d, lo, true);
}
__device__ __forceinline__ float i8d(unsigned v) {    // low byte as signed -> float
    return (float)(signed char)(v & 0xffu);
}

// ---------- pass A (1024-thread blocks): scatter FIRST, then qmark/misc/conv ----------
__global__ __launch_bounds__(1024) void bucket_scatter_k(
        const int* __restrict__ iu, const int* __restrict__ ii,
        const int* __restrict__ uid, const int* __restrict__ iid,
        int* __restrict__ cursor /*stride 16 ints*/, unsigned* __restrict__ pairs,
        unsigned char* __restrict__ qflag, unsigned char* __restrict__ flag,
        const float* __restrict__ lw, float* __restrict__ w4,
        float* __restrict__ dinv, float* __restrict__ z1scale,
        const float* __restrict__ ue, const float* __restrict__ ie,
        unsigned char* __restrict__ semb, unsigned char* __restrict__ z1,
        _Float16* __restrict__ z2) {
    int tid = threadIdx.x;
    if (blockIdx.x < SCAT_BLOCKS) {
        __shared__ int hist[NBKT];
        __shared__ int gbase[NBKT];
        int bid = blockIdx.x;
        for (int b = tid; b < NBKT; b += 1024) hist[b] = 0;
        __syncthreads();

        int e0 = bid * EDGES_PER_BLOCK;
        int u[4], it[4];
        unsigned pk[8];
        #pragma unroll
        for (int k = 0; k < 4; ++k) {
            int e = e0 + k * 1024 + tid;
            bool v = (e < NUM_INTER);
            u[k]  = v ? iu[e] : -1;
            it[k] = v ? (NUM_USERS + ii[e]) : -1;
        }
        #pragma unroll
        for (int k = 0; k < 4; ++k) {
            if (u[k] >= 0) {
                int b0 = u[k] >> BSHIFT;
                int r0 = atomicAdd(&hist[b0], 1);
                pk[2 * k] = ((unsigned)b0 << 13) | (unsigned)r0;    // lrank < 8192
                int b1 = it[k] >> BSHIFT;
                int r1 = atomicAdd(&hist[b1], 1);
                pk[2 * k + 1] = ((unsigned)b1 << 13) | (unsigned)r1;
            }
        }
        __syncthreads();
        for (int b = tid; b < NBKT; b += 1024) {
            int c = hist[b];
            if (c) gbase[b] = atomicAdd(&cursor[b * 16], c);
        }
        __syncthreads();
        #pragma unroll
        for (int k = 0; k < 4; ++k) {
            if (u[k] >= 0) {
                unsigned p0 = pk[2 * k];
                int b0 = (int)(p0 >> 13);
                int s0 = gbase[b0] + (int)(p0 & 0x1fffu);
                if (s0 < CAP)
                    pairs[(size_t)b0 * CAP + s0] =
                        ((unsigned)(u[k] & (BNODES - 1)) << 19) | (unsigned)it[k];
                unsigned p1 = pk[2 * k + 1];
                int b1 = (int)(p1 >> 13);
                int s1 = gbase[b1] + (int)(p1 & 0x1fffu);
                if (s1 < CAP)
                    pairs[(size_t)b1 * CAP + s1] =
                        ((unsigned)(it[k] & (BNODES - 1)) << 19) | (unsigned)u[k];
            }
        }
        return;
    }
    if (blockIdx.x < MISC_BLOCK) {
        int t = (blockIdx.x - QMARK_BASE) * 1024 + tid;   // < BATCH*2 exactly
        int node = (t & 1) ? (NUM_USERS + iid[t >> 1]) : uid[t >> 1];
        qflag[node] = 1;
        flag[node]  = 1;                                  // queried nodes need z2 too
        return;
    }
    if (blockIdx.x == MISC_BLOCK) {
        // misc: zero dummy rows (semb/z1 64 B, z2 128 B) + padding slots + softmax
        if (tid < 16)               ((unsigned*)semb)[(size_t)N_NODES * 16 + tid]      = 0u;
        if (tid >= 32 && tid < 48)  ((unsigned*)z1)[(size_t)N_NODES * 16 + (tid - 32)] = 0u;
        if (tid >= 64 && tid < 96)  ((unsigned*)z2)[(size_t)N_NODES * 32 + (tid - 64)] = 0u;
        if (tid == 96) dinv[N_NODES] = 0.0f;          // padding lanes gather dinv[N_NODES]
        if (tid == 97) z1scale[N_NODES] = 0.0f;       // guard: 0 x garbage would NaN
        if (tid == 0) {
            float a = lw[0], b = lw[1], c = lw[2], d = lw[3];
            float m = fmaxf(fmaxf(a, b), fmaxf(c, d));
            float e0 = expf(a - m), e1 = expf(b - m), e2 = expf(c - m), e3 = expf(d - m);
            float sm = e0 + e1 + e2 + e3;
            w4[0] = e0 / sm; w4[1] = e1 / sm; w4[2] = e2 / sm; w4[3] = e3 / sm;
        }
        return;
    }
    // conv: semb[n] = fp8(emb[n] * 256)   (64 B rows, no degree dependency)
    int t = (blockIdx.x - CONV_BASE) * 1024 + tid;
    int node = t >> 3;
    int q = t & 7;
    if (node >= N_NODES) return;
    const float4* src = (node < NUM_USERS)
        ? (const float4*)ue + (size_t)node * 16
        : (const float4*)ie + (size_t)(node - NUM_USERS) * 16;
    float4 f0 = src[q * 2];
    float4 f1 = src[q * 2 + 1];
    unsigned b0 = fp8pack4(f0.x * FP8_SCALE, f0.y * FP8_SCALE,
                           f0.z * FP8_SCALE, f0.w * FP8_SCALE);
    unsigned b1 = fp8pack4(f1.x * FP8_SCALE, f1.y * FP8_SCALE,
                           f1.z * FP8_SCALE, f1.w * FP8_SCALE);
    ((uint2*)semb)[(size_t)node * 8 + q] = make_uint2(b0, b1);
}

// ---------- pass B: bucket-local CSR, 1024 threads, pairs staged in LDS ----------
__global__ __launch_bounds__(1024) void bucket_all_k(
        const int* __restrict__ cursor, const unsigned* __restrict__ pairs,
        const unsigned char* __restrict__ qflag, unsigned char* __restrict__ flag,
        int* __restrict__ deg, float* __restrict__ dinv, float* __restrict__ d2,
        float* __restrict__ rcp, int* __restrict__ row_start, int* __restrict__ nbr) {
    __shared__ unsigned pl[CAP];          // 24 KB: this bucket's pairs (read once)
    __shared__ int cnt[BNODES];
    __shared__ int lofs_s[BNODES];
    __shared__ int sc[BNODES];
    __shared__ unsigned qf[BNODES / 4];
    int b = blockIdx.x, tid = threadIdx.x;
    if (tid < BNODES) cnt[tid] = 0;
    if (tid < BNODES / 4)
        qf[tid] = ((const unsigned*)(qflag + ((size_t)b << BSHIFT)))[tid];
    __syncthreads();
    int n = cursor[b * 16]; if (n > CAP) n = CAP;
    const unsigned* p = pairs + (size_t)b * CAP;
    const unsigned char* qfb = (const unsigned char*)qf;
    for (int j = tid; j < n; j += 1024) {
        unsigned code = p[j];
        pl[j] = code;                         // stage for the scatter pass
        int l = (int)(code >> 19);
        atomicAdd(&cnt[l], 1);
        if (qfb[l]) flag[code & PMASK] = 1;   // neighbor-of-queried
    }
    __syncthreads();

    int c = 0, pd = 0;
    if (tid < BNODES) { c = cnt[tid]; pd = (c + 3) & ~3; sc[tid] = pd; }
    __syncthreads();
    for (int o = 1; o < BNODES; o <<= 1) {
        int x = (tid >= o && tid < BNODES) ? sc[tid - o] : 0;
        __syncthreads();
        if (tid < BNODES) sc[tid] += x;
        __syncthreads();
    }
    if (tid < BNODES) {
        int excl = sc[tid] - pd;
        int g = (b << BSHIFT) + tid;
        if (g < N_NODES) {
            deg[g] = c;
            float fd = (float)c;
            dinv[g] = (c > 0) ? (1.0f / sqrtf(fd)) : 0.0f;
            d2[g]   = (c > 0) ? (1.0f / fd) : 0.0f;
            rcp[g]  = (c > 0) ? sqrtf(fd) : 0.0f;
            row_start[g] = (b << RSHIFT) + excl;
        }
        lofs_s[tid] = excl;
        cnt[tid] = 0;                 // reuse as rank counters
    }
    __syncthreads();

    int nbase = b << RSHIFT;
    for (int j = tid; j < n; j += 1024) {
        unsigned code = pl[j];                // LDS, not global
        int l = (int)(code >> 19);
        int r = atomicAdd(&cnt[l], 1);
        nbr[nbase + lofs_s[l] + r] = (int)(code & PMASK);
    }
}

// ---------- prop layer 1: z1 = int8rowquant( d2/256 * sum dinv * fp8semb ) ----------
__global__ void prop_first_k(const int* __restrict__ row_start, const int* __restrict__ nbr,
                             const int* __restrict__ deg, const float* __restrict__ d2,
                             const float* __restrict__ dinv,
                             const unsigned char* __restrict__ semb,
                             unsigned char* __restrict__ z1, float* __restrict__ z1scale) {
    int t = blockIdx.x * blockDim.x + threadIdx.x;
    int node = t >> 3;
    int q = t & 7;
    if (node >= N_NODES) return;
    int d = deg[node];
    int beg = row_start[node];
    int lim = beg + d;
    int end = beg + ((d + 3) & ~3);
    const uint2* src = (const uint2*)semb;    // 64 B rows: 8 threads x 8 B
    float a0 = 0.f, a1 = 0.f, a2 = 0.f, a3 = 0.f, a4 = 0.f, a5 = 0.f, a6 = 0.f, a7 = 0.f;
    for (int j = beg; j < end; j += 8) {
        vint4 na = __builtin_nontemporal_load((const vint4*)(nbr + j));
        vint4 nb = __builtin_nontemporal_load((const vint4*)(nbr + j + 4));
        #pragma unroll
        for (int k = 0; k < 8; ++k) {
            int id = (j + k < lim) ? ((k < 4) ? na[k] : nb[k - 4]) : N_NODES;
            float w = dinv[id];                  // dinv[N_NODES] == 0 (misc block)
            uint2 raw = src[(size_t)id * 8 + q];
            floatx2 p0 = fp8d2<false>(raw.x);    // HW v_cvt_pk_f32_fp8
            floatx2 p1 = fp8d2<true>(raw.x);
            floatx2 p2 = fp8d2<false>(raw.y);
            floatx2 p3 = fp8d2<true>(raw.y);
            a0 += w * p0.x; a1 += w * p0.y; a2 += w * p1.x; a3 += w * p1.y;
            a4 += w * p2.x; a5 += w * p2.y; a6 += w * p3.x; a7 += w * p3.y;
        }
    }
    float s = d2[node] * FP8_INVSCALE;           // undo the x256 fp8 staging scale
    float v0 = s * a0, v1 = s * a1, v2 = s * a2, v3 = s * a3;
    float v4 = s * a4, v5 = s * a5, v6 = s * a6, v7 = s * a7;
    // per-row (64-elem) max across this node's 8 lanes
    float m = fmaxf(fmaxf(fmaxf(fabsf(v0), fabsf(v1)), fmaxf(fabsf(v2), fabsf(v3))),
                    fmaxf(fmaxf(fabsf(v4), fabsf(v5)), fmaxf(fabsf(v6), fabsf(v7))));
    m = fmaxf(m, __shfl_xor(m, 1));
    m = fmaxf(m, __shfl_xor(m, 2));
    m = fmaxf(m, __shfl_xor(m, 4));
    float inv = (m > 0.f) ? (127.0f / m) : 0.0f;
    int b0 = __float2int_rn(v0 * inv), b1 = __float2int_rn(v1 * inv);
    int b2 = __float2int_rn(v2 * inv), b3 = __float2int_rn(v3 * inv);
    int b4 = __float2int_rn(v4 * inv), b5 = __float2int_rn(v5 * inv);
    int b6 = __float2int_rn(v6 * inv), b7 = __float2int_rn(v7 * inv);
    unsigned lo = (unsigned)(b0 & 255) | ((unsigned)(b1 & 255) << 8)
                | ((unsigned)(b2 & 255) << 16) | ((unsigned)(b3 & 255) << 24);
    unsigned hi = (unsigned)(b4 & 255) | ((unsigned)(b5 & 255) << 8)
                | ((unsigned)(b6 & 255) << 16) | ((unsigned)(b7 & 255) << 24);
    ((uint2*)z1)[(size_t)node * 8 + q] = make_uint2(lo, hi);
    if (q == 0) z1scale[node] = (m > 0.f) ? (m / 127.0f) : 0.0f;
}

// ---------- prop layer 2 (flag-masked): z2 = fp16( d2 * sum scale[n]*int8z1[n] ) ----------
__global__ void prop_masked_k(const int* __restrict__ row_start, const int* __restrict__ nbr,
                              const int* __restrict__ deg, const float* __restrict__ d2,
                              const unsigned char* __restrict__ flag,
                              const unsigned char* __restrict__ in,
                              const float* __restrict__ z1s,
                              _Float16* __restrict__ out) {
    int t = blockIdx.x * blockDim.x + threadIdx.x;
    int node = t >> 3;
    int q = t & 7;
    if (node >= N_NODES) return;
    if (!flag[node]) return;   // z2 never read at unflagged nodes
    int d = deg[node];
    int beg = row_start[node];
    int lim = beg + d;
    int end = beg + ((d + 3) & ~3);
    const uint2* src = (const uint2*)in;      // 64 B int8 rows
    float a0 = 0.f, a1 = 0.f, a2 = 0.f, a3 = 0.f, a4 = 0.f, a5 = 0.f, a6 = 0.f, a7 = 0.f;
    for (int j = beg; j < end; j += 8) {
        vint4 na = __builtin_nontemporal_load((const vint4*)(nbr + j));
        vint4 nb = __builtin_nontemporal_load((const vint4*)(nbr + j + 4));
        #pragma unroll
        for (int k = 0; k < 8; ++k) {
            int id = (j + k < lim) ? ((k < 4) ? na[k] : nb[k - 4]) : N_NODES;
            float sc = z1s[id];                // z1scale[N_NODES] == 0
            uint2 raw = src[(size_t)id * 8 + q];
            a0 += sc * i8d(raw.x);
            a1 += sc * i8d(raw.x >> 8);
            a2 += sc * i8d(raw.x >> 16);
            a3 += sc * i8d(raw.x >> 24);
            a4 += sc * i8d(raw.y);
            a5 += sc * i8d(raw.y >> 8);
            a6 += sc * i8d(raw.y >> 16);
            a7 += sc * i8d(raw.y >> 24);
        }
    }
    float s = d2[node];
    half8 r;
    r[0] = (_Float16)(s * a0); r[1] = (_Float16)(s * a1);
    r[2] = (_Float16)(s * a2); r[3] = (_Float16)(s * a3);
    r[4] = (_Float16)(s * a4); r[5] = (_Float16)(s * a5);
    r[6] = (_Float16)(s * a6); r[7] = (_Float16)(s * a7);
    ((half8*)out)[(size_t)node * 8 + q] = r;  // plain store: z2 re-read by score
}

// ---------- fused epilogue: layer-3 pull at queried nodes + layers 0-2 + dot ----------
// 16 lanes per (u,i) pair: 8 lanes user side, 8 lanes item side, 8 dims/lane
__global__ void fused_score_k(const int* __restrict__ row_start, const int* __restrict__ nbr,
                              const int* __restrict__ deg,
                              const float* __restrict__ dinv, const float* __restrict__ rcp,
                              const float* __restrict__ ue, const float* __restrict__ ie,
                              const unsigned char* __restrict__ z1,
                              const float* __restrict__ z1s,
                              const _Float16* __restrict__ z2,
                              const int* __restrict__ uid, const int* __restrict__ iid,
                              const float* __restrict__ w4, float* __restrict__ out) {
    int t = blockIdx.x * blockDim.x + threadIdx.x;
    int slot = t >> 4;
    if (slot >= BATCH) return;
    int within = t & 15;
    int side = within >> 3;
    int q = within & 7;

    int node;
    const float4* erow;
    if (side == 0) {
        int u = uid[slot];
        node = u;
        erow = (const float4*)ue + (size_t)u * 16;
    } else {
        int ii_ = iid[slot];
        node = NUM_USERS + ii_;
        erow = (const float4*)ie + (size_t)ii_ * 16;
    }

    float w0 = w4[0], w1 = w4[1], w2 = w4[2], w3 = w4[3];
    int d = deg[node];
    int beg = row_start[node];
    int lim = beg + d;
    int end = beg + ((d + 3) & ~3);
    const half8* z2v = (const half8*)z2;

    float a0 = 0.f, a1 = 0.f, a2 = 0.f, a3 = 0.f, a4 = 0.f, a5 = 0.f, a6 = 0.f, a7 = 0.f;
    for (int j = beg; j < end; j += 8) {
        vint4 na = __builtin_nontemporal_load((const vint4*)(nbr + j));
        vint4 nb = __builtin_nontemporal_load((const vint4*)(nbr + j + 4));
        #pragma unroll
        for (int k = 0; k < 8; ++k) {
            int id = (j + k < lim) ? ((k < 4) ? na[k] : nb[k - 4]) : N_NODES;
            half8 h = z2v[(size_t)id * 8 + q];
            a0 += (float)h[0]; a1 += (float)h[1]; a2 += (float)h[2]; a3 += (float)h[3];
            a4 += (float)h[4]; a5 += (float)h[5]; a6 += (float)h[6]; a7 += (float)h[7];
        }
    }

    float r  = rcp[node];
    float di = dinv[node];
    float e[8];
    *reinterpret_cast<float4*>(&e[0]) = erow[q * 2];
    *reinterpret_cast<float4*>(&e[4]) = erow[q * 2 + 1];
    uint2 r1 = ((const uint2*)z1)[(size_t)node * 8 + q];
    float s1 = z1s[node];
    float h1[8] = { s1 * i8d(r1.x),       s1 * i8d(r1.x >> 8),
                    s1 * i8d(r1.x >> 16), s1 * i8d(r1.x >> 24),
                    s1 * i8d(r1.y),       s1 * i8d(r1.y >> 8),
                    s1 * i8d(r1.y >> 16), s1 * i8d(r1.y >> 24) };
    half8 h2 = z2v[(size_t)node * 8 + q];
    float acc[8] = {a0, a1, a2, a3, a4, a5, a6, a7};

    float f[8];
    #pragma unroll
    for (int dd = 0; dd < 8; ++dd)
        f[dd] = w0 * e[dd] + r * (w1 * h1[dd] + w2 * (float)h2[dd]) + w3 * di * acc[dd];

    float pr = 0.f;
    #pragma unroll
    for (int dd = 0; dd < 8; ++dd) {
        float o = __shfl_xor(f[dd], 8);   // partner side, same dims
        pr += f[dd] * o;
    }
    pr += __shfl_xor(pr, 1);
    pr += __shfl_xor(pr, 2);
    pr += __shfl_xor(pr, 4);

    if (within == 0) out[slot] = pr;
}

// ---------- launch ----------

extern "C" void kernel_launch(void* const* d_in, const int* in_sizes, int n_in,
                              void* d_out, int out_size, void* d_ws, size_t ws_size,
                              hipStream_t stream) {
    const float* user_emb = (const float*)d_in[0];
    const float* item_emb = (const float*)d_in[1];
    const float* layer_w  = (const float*)d_in[2];
    const int*   inter_u  = (const int*)d_in[3];
    const int*   inter_i  = (const int*)d_in[4];
    const int*   user_ids = (const int*)d_in[5];
    const int*   item_ids = (const int*)d_in[6];
    float* out = (float*)d_out;

    char* base = (char*)d_ws;
    size_t off = 0;
    auto alloc = [&](size_t bytes) -> char* {
        char* p = base + off;
        off = (off + bytes + 255) & ~(size_t)255;
        return p;
    };
    float*    w4        = (float*)    alloc(4 * sizeof(float));
    int*      deg       = (int*)      alloc((size_t)N_NODES * sizeof(int));
    float*    dinv      = (float*)    alloc(((size_t)N_NODES + 1) * sizeof(float));  // +1: padding slot
    float*    d2        = (float*)    alloc((size_t)N_NODES * sizeof(float));
    float*    rcp       = (float*)    alloc((size_t)N_NODES * sizeof(float));
    float*    z1scale   = (float*)    alloc(((size_t)N_NODES + 1) * sizeof(float));  // +1: padding slot
    int*      row_start = (int*)      alloc((size_t)N_NODES * sizeof(int));
    // zeroed region: flag + qflag + cursor (adjacent; single memset)
    unsigned char* flag   = (unsigned char*)alloc((size_t)N_NODES + 256);
    unsigned char* qflag  = (unsigned char*)alloc((size_t)N_NODES + 512);
    int*           cursor = (int*)          alloc((size_t)NBKT * 16 * sizeof(int));
    unsigned* pairs     = (unsigned*) alloc((size_t)NBKT * CAP * sizeof(unsigned));
    int*      csr_nbr   = (int*)      alloc((size_t)NBKT * RSLOTS * sizeof(int));
    unsigned char* semb = (unsigned char*)alloc(((size_t)N_NODES + 1) * EMB);        // fp8 e4m3
    unsigned char* zB   = (unsigned char*)alloc(((size_t)N_NODES + 1) * EMB);        // int8 z1
    _Float16* zA        = (_Float16*) alloc(((size_t)N_NODES + 1) * EMB * sizeof(_Float16)); // fp16 z2

    // 1. zero flag + qflag + bucket cursors (adjacent allocations, single memset)
    size_t span = (size_t)((char*)cursor - (char*)flag) + (size_t)NBKT * 16 * sizeof(int);
    (void)hipMemsetAsync(flag, 0, span, stream);

    // 2. scatter-first 1024-thread dispatch: scatter + qmark + misc + fp8 emb cast
    bucket_scatter_k<<<CONV_BASE + CONV_BLOCKS, 1024, 0, stream>>>(
        inter_u, inter_i, user_ids, item_ids, cursor, pairs, qflag, flag,
        layer_w, w4, dinv, z1scale, user_emb, item_emb, semb, zB, zA);

    // 3. bucket-local CSR: degrees + factors + row_start + scatter (LDS-staged pairs)
    bucket_all_k<<<NBKT, 1024, 0, stream>>>(
        cursor, pairs, qflag, flag, deg, dinv, d2, rcp, row_start, csr_nbr);

    // 4. layer 1 full (fp8 gather via HW cvt, int8 row-quant z1 out): zB = z1
    prop_first_k<<<PROP_BLOCKS, 256, 0, stream>>>(
        row_start, csr_nbr, deg, d2, dinv, semb, zB, z1scale);

    // 5. layer 2 flag-masked (int8 z1 gather, fp16 z2 out): zA = z2
    prop_masked_k<<<PROP_BLOCKS, 256, 0, stream>>>(
        row_start, csr_nbr, deg, d2, flag, zB, z1scale, zA);

    // 6. fused: layer-3 pull at queried nodes + layer 0-2 terms + dot product
    fused_score_k<<<(BATCH * 16 + 255) / 256, 256, 0, stream>>>(
        row_start, csr_nbr, deg, dinv, rcp, user_emb, item_emb,
        zB /*z1*/, z1scale, zA /*z2*/, user_ids, item_ids, w4, out);
}